// Round 10
// baseline (174.930 us; speedup 1.0000x reference)
//
#include <hip/hip_runtime.h>
#include <hip/hip_bf16.h>

#define NB 4
#define CCH 256
#define CRD 32
#define NN 4096

typedef __attribute__((ext_vector_type(8))) short short8;
typedef __attribute__((ext_vector_type(4))) float floatx4;
typedef __attribute__((ext_vector_type(4))) int intx4;
typedef __attribute__((ext_vector_type(2))) unsigned int uintx2;

__device__ __forceinline__ unsigned short f2bf(float f) {
  unsigned u = __builtin_bit_cast(unsigned, f);
  u += 0x7FFFu + ((u >> 16) & 1u);
  return (unsigned short)(u >> 16);
}

// Clamped convert: finite bf16 regardless of input (NaN -> -1e4 via IEEE
// maxNum/minNum, +-inf -> +-1e4). Legit qkv values |v| < ~20: transparent.
__device__ __forceinline__ unsigned short f2bf_c(float f) {
  f = fminf(fmaxf(f, -1.0e4f), 1.0e4f);
  unsigned u = __builtin_bit_cast(unsigned, f);
  u += 0x7FFFu + ((u >> 16) & 1u);
  return (unsigned short)(u >> 16);
}

__device__ __forceinline__ unsigned pack2c(float a, float b) {
  return (unsigned)f2bf_c(a) | ((unsigned)f2bf_c(b) << 16);
}

// Output sanitizer: NaN -> -1e30 (IEEE maxNum), +-inf -> +-1e30.
__device__ __forceinline__ float sat(float v) {
  return fminf(fmaxf(v, -1.0e30f), 1.0e30f);
}

__device__ __forceinline__ short8 ld_frag_g(const unsigned short* p) {
  return __builtin_bit_cast(short8, *(const intx4*)p);
}

// ---------------------------------------------------------------------------
// Kernel 0: convert Wq/Wk/Wv fp32 -> one bf16 matrix Wb[320][256] (proven r2).
// Rows 0..31 = Wq, 32..63 = Wk, 64..319 = Wv. Runs once, ~2 us.
// ---------------------------------------------------------------------------
__global__ __launch_bounds__(256) void w_convert(
    const float* __restrict__ Wq, const float* __restrict__ Wk,
    const float* __restrict__ Wv, unsigned short* __restrict__ Wb)
{
  const int t    = blockIdx.x * 256 + threadIdx.x;  // 80 blocks * 256 = 20480
  const int row  = t >> 6;                          // 64 float4 per 256-col row
  const int col4 = t & 63;
  const float* src = (row < 32) ? Wq + (size_t)row * CCH
                   : (row < 64) ? Wk + (size_t)(row - 32) * CCH
                                : Wv + (size_t)(row - 64) * CCH;
  const floatx4 f = *(const floatx4*)(src + col4 * 4);
  uintx2 u;
  u[0] = pack2c(f[0], f[1]);
  u[1] = pack2c(f[2], f[3]);
  *(uintx2*)(Wb + (size_t)row * CCH + col4 * 4) = u;
}

// ---------------------------------------------------------------------------
// Kernel 1: QKV GEMM, round-10 rewrite of the staging path:
//  - W NEVER goes through LDS: the MFMA A-frag is a 16B-aligned contiguous
//    global load Wb[(base+ms*16+lm)*256 + k0*32 + lq*8]. W tile = 32 KB
//    bf16, L1/L2-resident, shared across co-resident blocks. This deletes
//    per-mt: 16 fp32 dwordx4 loads + 32 f2bf packs + 16 LDS writes per
//    thread + 2 barriers.
//  - x staged once into xs (transpose+convert, unchanged scheme).
//  - V epilogue bounces through a dedicated 8 KB vb2 (ws is gone).
//  LDS 41.8 KB/block -> 2 blocks/CU at grid (64,2,4)=512.
// ---------------------------------------------------------------------------
__global__ __launch_bounds__(256, 2) void gemm_qkv2(
    const float* __restrict__ x, const unsigned short* __restrict__ Wb,
    const float* __restrict__ bq, const float* __restrict__ bk,
    const float* __restrict__ bv,
    unsigned short* __restrict__ qT, unsigned short* __restrict__ kT,
    unsigned short* __restrict__ vv)
{
  __shared__ __align__(16) unsigned short xs[64 * 264];
  __shared__ __align__(16) unsigned short vb2[64 * 64];

  const int tid  = threadIdx.x;
  const int wave = tid >> 6;          // n-fragment 0..3 (16 n each)
  const int lane = tid & 63;
  const int lq   = lane >> 4;
  const int lm   = lane & 15;
  const int n0   = blockIdx.x << 6;
  const int mg   = blockIdx.y;
  const int b    = blockIdx.z;

  // stage x[b][0:256][n0:n0+64] -> xs[n][c] bf16 (transpose + convert)
  {
    const int nn = lane;
    const int cg = wave;
    const float* xb = x + ((size_t)b << 20) + n0 + nn;
#pragma unroll
    for (int it = 0; it < 16; ++it) {
      const int c0 = it * 16 + cg * 4;
      const float v0 = xb[(size_t)(c0 + 0) << 12];
      const float v1 = xb[(size_t)(c0 + 1) << 12];
      const float v2 = xb[(size_t)(c0 + 2) << 12];
      const float v3 = xb[(size_t)(c0 + 3) << 12];
      uintx2 u;
      u[0] = pack2c(v0, v1);
      u[1] = pack2c(v2, v3);
      *(uintx2*)(xs + nn * 264 + c0) = u;
    }
  }
  __syncthreads();   // xs ready; stays read-only for the rest of the kernel

  const int mt_lo = mg ? 3 : 0;
  const int mt_hi = mg ? 5 : 3;

#pragma unroll 1
  for (int mt = mt_lo; mt < mt_hi; ++mt) {
    const unsigned short* wtile = Wb + (size_t)(mt * 64) * CCH;

    floatx4 acc[4];
#pragma unroll
    for (int t = 0; t < 4; ++t) acc[t] = (floatx4){0.f, 0.f, 0.f, 0.f};

#pragma unroll 2
    for (int k0 = 0; k0 < 8; ++k0) {
      short8 af[4];
#pragma unroll
      for (int ms = 0; ms < 4; ++ms)
        af[ms] = ld_frag_g(wtile + (size_t)(ms * 16 + lm) * CCH +
                           k0 * 32 + lq * 8);
      const short8 bf = __builtin_bit_cast(short8,
          *(const intx4*)(xs + (wave * 16 + lm) * 264 + k0 * 32 + lq * 8));
#pragma unroll
      for (int ms = 0; ms < 4; ++ms)
        acc[ms] = __builtin_amdgcn_mfma_f32_16x16x32_bf16(af[ms], bf,
                                                          acc[ms], 0, 0, 0);
    }

    if (mt == 0) {
      // q/k epilogue: rows 0..31 = q, 32..63 = k (register-only; no barrier)
      const int n = n0 + wave * 16 + lm;
#pragma unroll
      for (int ms = 0; ms < 4; ++ms) {
        const int d0 = (ms & 1) * 16 + lq * 4;
        const float* bias = (ms < 2) ? bq : bk;
        unsigned short* dst = (ms < 2) ? qT : kT;
        uintx2 u;
        u[0] = pack2c(acc[ms][0] + bias[d0],     acc[ms][1] + bias[d0 + 1]);
        u[1] = pack2c(acc[ms][2] + bias[d0 + 2], acc[ms][3] + bias[d0 + 3]);
        *(uintx2*)(dst + (size_t)(b * NN + n) * CRD + d0) = u;
      }
    } else {
      // V epilogue: bounce through vb2 [64c][64n] for coalesced stores
      const int cb = (mt - 1) * 64;
      __syncthreads();   // prior mt's vb2 reads complete before overwrite
#pragma unroll
      for (int ms = 0; ms < 4; ++ms)
#pragma unroll
        for (int r = 0; r < 4; ++r) {
          const int c = ms * 16 + lq * 4 + r;
          vb2[c * 64 + wave * 16 + lm] = f2bf_c(acc[ms][r] + bv[cb + c]);
        }
      __syncthreads();
#pragma unroll
      for (int it = 0; it < 2; ++it) {
        const int u = it * 256 + tid;
        const int m = u >> 3;
        const int o = (u & 7) * 8;
        *(intx4*)(vv + (size_t)(b * CCH + cb + m) * NN + n0 + o) =
            *(const intx4*)(vb2 + m * 64 + o);
      }
    }
  }
}

// ---------------------------------------------------------------------------
// Kernel 2: attention -- BYTE-IDENTICAL to round-9 (79.8 us stable; isolate
// the gemm variable this round).
// ---------------------------------------------------------------------------
__global__ __launch_bounds__(512) void attn_kernel(
    const float* __restrict__ x, const float* __restrict__ gamma_p,
    const unsigned short* __restrict__ qT, const unsigned short* __restrict__ kT,
    const unsigned short* __restrict__ vv, float* __restrict__ out)
{
  __shared__ __align__(16) unsigned char smem[65536 + 2 * 4 * 2176];

  const int tid  = threadIdx.x;
  const int wave = tid >> 6;
  const int wg   = wave >> 1;
  const int cs   = wave & 1;
  const int lane = tid & 63;
  const int lq   = lane >> 4;
  const int lm   = lane & 15;
  const int xcd = blockIdx.x & 7;
  const int pos = blockIdx.x >> 3;
  const int b   = xcd >> 1;
  const int i0  = (((xcd & 1) << 5) | pos) << 6;

  const unsigned short* kTb = kT + (size_t)b * NN * CRD;
  const unsigned short* vb  = vv + (size_t)b * CCH * NN;

  const short8 qf =
      ld_frag_g(qT + (size_t)(b * NN + i0 + wg * 16 + lm) * CRD + lq * 8);

  int vs_g[4];
  int vs_off[4];
#pragma unroll
  for (int m = 0; m < 4; ++m) {
    const int u  = m * 512 + tid;
    const int c  = u >> 3;
    const int jb = u & 7;
    vs_g[m]   = c * NN + jb * 8;
    vs_off[m] = c * 128 + ((jb ^ (c & 7)) * 16);
  }

  floatx4 acc[8];
#pragma unroll
  for (int t = 0; t < 8; ++t) acc[t] = (floatx4){0.f, 0.f, 0.f, 0.f};
  float lsum[4] = {0.f, 0.f, 0.f, 0.f};

  const floatx4 zf = {0.f, 0.f, 0.f, 0.f};

  // ---- prologue: build window 0 in parity 0, then prefetch window 1 ----
  intx4 vreg[4];
#pragma unroll
  for (int m = 0; m < 4; ++m)
    vreg[m] = *(const intx4*)(vb + vs_g[m]);
  short8 kf[2];
#pragma unroll
  for (int jt = 0; jt < 2; ++jt)
    kf[jt] = ld_frag_g(kTb + (size_t)((cs * 2 + jt) * 16 + lm) * CRD + lq * 8);

#pragma unroll
  for (int m = 0; m < 4; ++m)
    *(intx4*)(smem + vs_off[m]) = vreg[m];
  {
    unsigned char* pb0 = smem + 65536 + wg * 2176;
#pragma unroll
    for (int jt = 0; jt < 2; ++jt) {
      const floatx4 S = __builtin_amdgcn_mfma_f32_16x16x32_bf16(
          qf, kf[jt], zf, 0, 0, 0);
#pragma unroll
      for (int r = 0; r < 4; ++r) {
        const float p = __expf(fminf(fmaxf(S[r], -40.f), 40.f));
        lsum[r] += p;
        *(unsigned short*)(pb0 + (lq * 4 + r) * 136 +
                           (((cs * 2 + jt) * 16 + lm) << 1)) = f2bf(p);
      }
    }
  }
#pragma unroll
  for (int m = 0; m < 4; ++m)
    vreg[m] = *(const intx4*)(vb + vs_g[m] + 64);
#pragma unroll
  for (int jt = 0; jt < 2; ++jt)
    kf[jt] = ld_frag_g(kTb + (size_t)(64 + (cs * 2 + jt) * 16 + lm) * CRD +
                       lq * 8);

  // ---- main loop: k = 0..62, one barrier per iter, straight-line body ----
#pragma unroll 1
  for (int k = 0; k < 63; ++k) {
    asm volatile("s_waitcnt lgkmcnt(0)" ::: "memory");
    __builtin_amdgcn_s_barrier();

    unsigned char* vbp = smem + ((k & 1) << 15);
    unsigned char* pbp = smem + 65536 + (k & 1) * 8704 + wg * 2176;
    unsigned char* vbn = smem + (((k + 1) & 1) << 15);
    unsigned char* pbn = smem + 65536 + ((k + 1) & 1) * 8704 + wg * 2176;

    // stage V(k+1) into parity k+1 (vreg prefetched last iter)
#pragma unroll
    for (int m = 0; m < 4; ++m)
      *(intx4*)(vbn + vs_off[m]) = vreg[m];

    // QK(k+1) + exp + P-store(k+1) -> parity k+1 (independent of PV(k))
#pragma unroll
    for (int jt = 0; jt < 2; ++jt) {
      const floatx4 S = __builtin_amdgcn_mfma_f32_16x16x32_bf16(
          qf, kf[jt], zf, 0, 0, 0);
#pragma unroll
      for (int r = 0; r < 4; ++r) {
        const float p = __expf(fminf(fmaxf(S[r], -40.f), 40.f));
        lsum[r] += p;
        *(unsigned short*)(pbn + (lq * 4 + r) * 136 +
                           (((cs * 2 + jt) * 16 + lm) << 1)) = f2bf(p);
      }
    }

    // prefetch window k+2 (clamped; redundant at k=62, branch-free body)
    {
      const int j2 = ((k + 2 < 64) ? (k + 2) : 63) << 6;
#pragma unroll
      for (int m = 0; m < 4; ++m)
        vreg[m] = *(const intx4*)(vb + vs_g[m] + j2);
#pragma unroll
      for (int jt = 0; jt < 2; ++jt)
        kf[jt] = ld_frag_g(kTb +
                           (size_t)(j2 + (cs * 2 + jt) * 16 + lm) * CRD + lq * 8);
    }

    // PV(k): this wave's 128-col c-half; reads V/P parity k
#pragma unroll
    for (int ks = 0; ks < 2; ++ks) {
      const unsigned char* pa = pbp + lm * 136 + ks * 64 + lq * 16;
      struct U128 { unsigned long long a, b; } pp;
      pp.a = *(const unsigned long long*)pa;
      pp.b = *(const unsigned long long*)(pa + 8);
      const short8 pf = __builtin_bit_cast(short8, pp);
#pragma unroll
      for (int nt = 0; nt < 8; ++nt) {
        const int c = cs * 128 + nt * 16 + lm;
        const short8 vf = __builtin_bit_cast(
            short8,
            *(const intx4*)(vbp + c * 128 + (((ks * 4 + lq) ^ (lm & 7)) * 16)));
        acc[nt] = __builtin_amdgcn_mfma_f32_16x16x32_bf16(pf, vf, acc[nt],
                                                          0, 0, 0);
      }
    }
  }

  // ---- epilogue iteration: PV(63), parity 1 ----
  asm volatile("s_waitcnt lgkmcnt(0)" ::: "memory");
  __builtin_amdgcn_s_barrier();
  {
    const unsigned char* vbp = smem + (1 << 15);
    const unsigned char* pbp = smem + 65536 + 8704 + wg * 2176;
#pragma unroll
    for (int ks = 0; ks < 2; ++ks) {
      const unsigned char* pa = pbp + lm * 136 + ks * 64 + lq * 16;
      struct U128 { unsigned long long a, b; } pp;
      pp.a = *(const unsigned long long*)pa;
      pp.b = *(const unsigned long long*)(pa + 8);
      const short8 pf = __builtin_bit_cast(short8, pp);
#pragma unroll
      for (int nt = 0; nt < 8; ++nt) {
        const int c = cs * 128 + nt * 16 + lm;
        const short8 vf = __builtin_bit_cast(
            short8,
            *(const intx4*)(vbp + c * 128 + (((ks * 4 + lq) ^ (lm & 7)) * 16)));
        acc[nt] = __builtin_amdgcn_mfma_f32_16x16x32_bf16(pf, vf, acc[nt],
                                                          0, 0, 0);
      }
    }
  }

  // combine partial lsum across the cs wave pair (each saw half the j's)
  __syncthreads();
  floatx4 lv;
#pragma unroll
  for (int r = 0; r < 4; ++r) lv[r] = lsum[r];
  *(floatx4*)(smem + ((wave * 64 + lane) << 4)) = lv;
  __syncthreads();
  const floatx4 lpart = *(const floatx4*)(smem + (((wave ^ 1) * 64 + lane) << 4));

  float inv[4];
#pragma unroll
  for (int r = 0; r < 4; ++r) {
    float v = lsum[r] + lpart[r];
    v += __shfl_xor(v, 1);
    v += __shfl_xor(v, 2);
    v += __shfl_xor(v, 4);
    v += __shfl_xor(v, 8);
    inv[r] = 1.0f / v;
  }

  const float gm = gamma_p[0];
#pragma unroll
  for (int nt = 0; nt < 8; ++nt) {
#pragma unroll
    for (int r = 0; r < 4; ++r) {
      const int c = cs * 128 + nt * 16 + lm;
      const int i = i0 + wg * 16 + lq * 4 + r;
      const size_t idx = (size_t)(b * CCH + c) * NN + i;
      out[idx] = gm * sat(acc[nt][r] * inv[r]) + x[idx];
    }
  }
}

extern "C" void kernel_launch(void* const* d_in, const int* in_sizes, int n_in,
                              void* d_out, int out_size, void* d_ws, size_t ws_size,
                              hipStream_t stream) {
  (void)in_sizes; (void)n_in; (void)out_size; (void)ws_size;
  const float* x     = (const float*)d_in[0];
  const float* Wq    = (const float*)d_in[1];
  const float* bq    = (const float*)d_in[2];
  const float* Wk    = (const float*)d_in[3];
  const float* bk    = (const float*)d_in[4];
  const float* Wv    = (const float*)d_in[5];
  const float* bv    = (const float*)d_in[6];
  const float* gamma = (const float*)d_in[7];

  unsigned short* qT = (unsigned short*)d_ws;              // 1 MiB
  unsigned short* kT = qT + (size_t)NB * NN * CRD;         // 1 MiB
  unsigned short* vv = kT + (size_t)NB * NN * CRD;         // 8 MiB
  // d_out doubles as scratch before attn overwrites it: Wb bf16 at +8 MiB
  unsigned short* Wb = (unsigned short*)d_out + (size_t)NB * NN * CCH;

  w_convert<<<dim3(80), 256, 0, stream>>>(Wq, Wk, Wv, Wb);
  gemm_qkv2<<<dim3(64, 2, 4), 256, 0, stream>>>(x, Wb, bq, bk, bv,
                                                qT, kT, vv);
  attn_kernel<<<dim3(256, 1, 1), 512, 0, stream>>>(x, gamma, qT, kT, vv,
                                                   (float*)d_out);
}

// Round 11
// 169.080 us; speedup vs baseline: 1.0346x; 1.0346x over previous
//
#include <hip/hip_runtime.h>
#include <hip/hip_bf16.h>

#define NB 4
#define CCH 256
#define CRD 32
#define NN 4096

typedef __attribute__((ext_vector_type(8))) short short8;
typedef __attribute__((ext_vector_type(4))) float floatx4;
typedef __attribute__((ext_vector_type(4))) int intx4;
typedef __attribute__((ext_vector_type(2))) unsigned int uintx2;

__device__ __forceinline__ unsigned short f2bf(float f) {
  unsigned u = __builtin_bit_cast(unsigned, f);
  u += 0x7FFFu + ((u >> 16) & 1u);
  return (unsigned short)(u >> 16);
}

// Clamped convert: finite bf16 regardless of input (NaN -> -1e4 via IEEE
// maxNum/minNum, +-inf -> +-1e4). Legit qkv values |v| < ~20: transparent.
__device__ __forceinline__ unsigned short f2bf_c(float f) {
  f = fminf(fmaxf(f, -1.0e4f), 1.0e4f);
  unsigned u = __builtin_bit_cast(unsigned, f);
  u += 0x7FFFu + ((u >> 16) & 1u);
  return (unsigned short)(u >> 16);
}

__device__ __forceinline__ unsigned pack2c(float a, float b) {
  return (unsigned)f2bf_c(a) | ((unsigned)f2bf_c(b) << 16);
}

// Output sanitizer: NaN -> -1e30 (IEEE maxNum), +-inf -> +-1e30.
__device__ __forceinline__ float sat(float v) {
  return fminf(fmaxf(v, -1.0e30f), 1.0e30f);
}

__device__ __forceinline__ short8 ld_frag_g(const unsigned short* p) {
  return __builtin_bit_cast(short8, *(const intx4*)p);
}

// ---------------------------------------------------------------------------
// Kernel 1: fused transpose + QKV GEMM -- REVERTED to the round-9 version
// (best measured total). r10's W-from-global variant regressed ~15 us.
// ---------------------------------------------------------------------------
__global__ __launch_bounds__(256) void gemm_qkv_fused(
    const float* __restrict__ x,
    const float* __restrict__ Wq, const float* __restrict__ bq,
    const float* __restrict__ Wk, const float* __restrict__ bk,
    const float* __restrict__ Wv, const float* __restrict__ bv,
    unsigned short* __restrict__ qT, unsigned short* __restrict__ kT,
    unsigned short* __restrict__ vv)
{
  __shared__ __align__(16) unsigned short xs[64 * 264];
  __shared__ __align__(16) unsigned short ws[64 * 264];

  const int tid  = threadIdx.x;
  const int wave = tid >> 6;
  const int lane = tid & 63;
  const int lq   = lane >> 4;
  const int lm   = lane & 15;
  const int n0   = blockIdx.x << 6;
  const int mg   = blockIdx.y;
  const int b    = blockIdx.z;

  {
    const int nn = lane;
    const int cg = wave;
    const float* xb = x + ((size_t)b << 20) + n0 + nn;
#pragma unroll
    for (int it = 0; it < 16; ++it) {
      const int c0 = it * 16 + cg * 4;
      const float v0 = xb[(size_t)(c0 + 0) << 12];
      const float v1 = xb[(size_t)(c0 + 1) << 12];
      const float v2 = xb[(size_t)(c0 + 2) << 12];
      const float v3 = xb[(size_t)(c0 + 3) << 12];
      uintx2 u;
      u[0] = pack2c(v0, v1);
      u[1] = pack2c(v2, v3);
      *(uintx2*)(xs + nn * 264 + c0) = u;
    }
  }

  const int mt_lo = mg ? 3 : 0;
  const int mt_hi = mg ? 5 : 3;

  for (int mt = mt_lo; mt < mt_hi; ++mt) {
#pragma unroll
    for (int i = 0; i < 16; ++i) {
      const int u  = i * 256 + tid;
      const int m  = u >> 6;
      const int o4 = (u & 63) * 4;
      const float* src = (mt == 0)
          ? (m < 32 ? Wq + (size_t)m * CCH : Wk + (size_t)(m - 32) * CCH)
          : Wv + (size_t)((mt - 1) * 64 + m) * CCH;
      const floatx4 f = *(const floatx4*)(src + o4);
      uintx2 uu;
      uu[0] = pack2c(f[0], f[1]);
      uu[1] = pack2c(f[2], f[3]);
      *(uintx2*)(ws + m * 264 + o4) = uu;
    }
    __syncthreads();

    floatx4 acc[4];
#pragma unroll
    for (int t = 0; t < 4; ++t) acc[t] = (floatx4){0.f, 0.f, 0.f, 0.f};

#pragma unroll
    for (int k0 = 0; k0 < 8; ++k0) {
      short8 af[4];
#pragma unroll
      for (int ms = 0; ms < 4; ++ms)
        af[ms] = __builtin_bit_cast(short8,
            *(const intx4*)(ws + (ms * 16 + lm) * 264 + k0 * 32 + lq * 8));
      const short8 bf = __builtin_bit_cast(short8,
          *(const intx4*)(xs + (wave * 16 + lm) * 264 + k0 * 32 + lq * 8));
#pragma unroll
      for (int ms = 0; ms < 4; ++ms)
        acc[ms] = __builtin_amdgcn_mfma_f32_16x16x32_bf16(af[ms], bf,
                                                          acc[ms], 0, 0, 0);
    }
    __syncthreads();

    if (mt == 0) {
      const int n = n0 + wave * 16 + lm;
#pragma unroll
      for (int ms = 0; ms < 4; ++ms) {
        const int d0 = (ms & 1) * 16 + lq * 4;
        const float* bias = (ms < 2) ? bq : bk;
        unsigned short* dst = (ms < 2) ? qT : kT;
        uintx2 u;
        u[0] = pack2c(acc[ms][0] + bias[d0],     acc[ms][1] + bias[d0 + 1]);
        u[1] = pack2c(acc[ms][2] + bias[d0 + 2], acc[ms][3] + bias[d0 + 3]);
        *(uintx2*)(dst + (size_t)(b * NN + n) * CRD + d0) = u;
      }
    } else {
      const int cb = (mt - 1) * 64;
      unsigned short* vb2 = ws;
#pragma unroll
      for (int ms = 0; ms < 4; ++ms)
#pragma unroll
        for (int r = 0; r < 4; ++r) {
          const int c = ms * 16 + lq * 4 + r;
          vb2[c * 64 + wave * 16 + lm] = f2bf_c(acc[ms][r] + bv[cb + c]);
        }
      __syncthreads();
#pragma unroll
      for (int it = 0; it < 2; ++it) {
        const int u = it * 256 + tid;
        const int m = u >> 3;
        const int o = (u & 7) * 8;
        *(intx4*)(vv + (size_t)(b * CCH + cb + m) * NN + n0 + o) =
            *(const intx4*)(vb2 + m * 64 + o);
      }
      __syncthreads();
    }
  }
}

// ---------------------------------------------------------------------------
// Kernel 2: attention, round-11: C-SPLIT BLOCK PAIRS for 2 blocks/CU.
// r9 schedule/layout verbatim, but each block owns only 128 of the 256 V
// channels (ch = pos&1): per-CU V-staging bytes UNCHANGED (r3's failure
// doubled them), PV MFMA total unchanged, LDS 49.4 KB/block -> 2 blocks/CU
// = 4 waves/SIMD. QK+exp duplicated across the pair (VALU 27%->~50%, still
// headroom). Pure TLP/skew-hiding experiment, isolated this time.
// ---------------------------------------------------------------------------
__global__ __launch_bounds__(512) void attn_kernel(
    const float* __restrict__ x, const float* __restrict__ gamma_p,
    const unsigned short* __restrict__ qT, const unsigned short* __restrict__ kT,
    const unsigned short* __restrict__ vv, float* __restrict__ out)
{
  // [0,32768): V double buffer (2 x 128c x 64j bf16, swizzled)
  // [32768, +17408): P double buffer (2 parity x 4 wg x 16 i x 68col shorts)
  __shared__ __align__(16) unsigned char smem[32768 + 2 * 4 * 2176];

  const int tid  = threadIdx.x;
  const int wave = tid >> 6;
  const int wg   = wave >> 1;   // row-group 0..3 (16 rows each)
  const int cs   = wave & 1;    // c-quarter within half AND jt-half for QK
  const int lane = tid & 63;
  const int lq   = lane >> 4;
  const int lm   = lane & 15;
  const int xcd = blockIdx.x & 7;
  const int pos = blockIdx.x >> 3;       // 0..63
  const int ch  = pos & 1;               // c-half 0..1 (128 channels)
  const int ip  = pos >> 1;              // 0..31
  const int b   = xcd >> 1;
  const int i0  = (((xcd & 1) << 5) | ip) << 6;

  const unsigned short* kTb = kT + (size_t)b * NN * CRD;
  const unsigned short* vb  = vv + (size_t)(b * CCH + ch * 128) * NN;

  const short8 qf =
      ld_frag_g(qT + (size_t)(b * NN + i0 + wg * 16 + lm) * CRD + lq * 8);

  // per-lane V-stage coords: 1024 16B-units over [128 c][8 jb]; m < 2
  int vs_g[2];
  int vs_off[2];
#pragma unroll
  for (int m = 0; m < 2; ++m) {
    const int u  = m * 512 + tid;
    const int c  = u >> 3;                        // 0..127 (local channel)
    const int jb = u & 7;
    vs_g[m]   = c * NN + jb * 8;                  // + j0 at load time
    vs_off[m] = c * 128 + ((jb ^ (c & 7)) * 16);  // swizzled LDS slot
  }

  floatx4 acc[4];
#pragma unroll
  for (int t = 0; t < 4; ++t) acc[t] = (floatx4){0.f, 0.f, 0.f, 0.f};
  float lsum[4] = {0.f, 0.f, 0.f, 0.f};

  const floatx4 zf = {0.f, 0.f, 0.f, 0.f};

  // ---- prologue: build window 0 in parity 0, then prefetch window 1 ----
  intx4 vreg[2];
#pragma unroll
  for (int m = 0; m < 2; ++m)
    vreg[m] = *(const intx4*)(vb + vs_g[m]);
  short8 kf[2];
#pragma unroll
  for (int jt = 0; jt < 2; ++jt)
    kf[jt] = ld_frag_g(kTb + (size_t)((cs * 2 + jt) * 16 + lm) * CRD + lq * 8);

#pragma unroll
  for (int m = 0; m < 2; ++m)
    *(intx4*)(smem + vs_off[m]) = vreg[m];
  {
    unsigned char* pb0 = smem + 32768 + wg * 2176;
#pragma unroll
    for (int jt = 0; jt < 2; ++jt) {
      const floatx4 S = __builtin_amdgcn_mfma_f32_16x16x32_bf16(
          qf, kf[jt], zf, 0, 0, 0);
#pragma unroll
      for (int r = 0; r < 4; ++r) {
        const float p = __expf(fminf(fmaxf(S[r], -40.f), 40.f));
        lsum[r] += p;
        *(unsigned short*)(pb0 + (lq * 4 + r) * 136 +
                           (((cs * 2 + jt) * 16 + lm) << 1)) = f2bf(p);
      }
    }
  }
#pragma unroll
  for (int m = 0; m < 2; ++m)
    vreg[m] = *(const intx4*)(vb + vs_g[m] + 64);
#pragma unroll
  for (int jt = 0; jt < 2; ++jt)
    kf[jt] = ld_frag_g(kTb + (size_t)(64 + (cs * 2 + jt) * 16 + lm) * CRD +
                       lq * 8);

  // ---- main loop: k = 0..62, one lgkm-barrier per iter, straight-line ----
#pragma unroll 1
  for (int k = 0; k < 63; ++k) {
    asm volatile("s_waitcnt lgkmcnt(0)" ::: "memory");
    __builtin_amdgcn_s_barrier();

    unsigned char* vbp = smem + ((k & 1) << 14);
    unsigned char* pbp = smem + 32768 + (k & 1) * 8704 + wg * 2176;
    unsigned char* vbn = smem + (((k + 1) & 1) << 14);
    unsigned char* pbn = smem + 32768 + ((k + 1) & 1) * 8704 + wg * 2176;

    // stage V(k+1) into parity k+1 (vreg prefetched last iter)
#pragma unroll
    for (int m = 0; m < 2; ++m)
      *(intx4*)(vbn + vs_off[m]) = vreg[m];

    // QK(k+1) + exp + P-store(k+1) -> parity k+1 (independent of PV(k))
#pragma unroll
    for (int jt = 0; jt < 2; ++jt) {
      const floatx4 S = __builtin_amdgcn_mfma_f32_16x16x32_bf16(
          qf, kf[jt], zf, 0, 0, 0);
#pragma unroll
      for (int r = 0; r < 4; ++r) {
        const float p = __expf(fminf(fmaxf(S[r], -40.f), 40.f));
        lsum[r] += p;
        *(unsigned short*)(pbn + (lq * 4 + r) * 136 +
                           (((cs * 2 + jt) * 16 + lm) << 1)) = f2bf(p);
      }
    }

    // prefetch window k+2 (clamped; redundant at k=62, branch-free body)
    {
      const int j2 = ((k + 2 < 64) ? (k + 2) : 63) << 6;
#pragma unroll
      for (int m = 0; m < 2; ++m)
        vreg[m] = *(const intx4*)(vb + vs_g[m] + j2);
#pragma unroll
      for (int jt = 0; jt < 2; ++jt)
        kf[jt] = ld_frag_g(kTb +
                           (size_t)(j2 + (cs * 2 + jt) * 16 + lm) * CRD + lq * 8);
    }

    // PV(k): this wave's 64-channel quarter of the block's 128-c half
#pragma unroll
    for (int ks = 0; ks < 2; ++ks) {
      const unsigned char* pa = pbp + lm * 136 + ks * 64 + lq * 16;
      struct U128 { unsigned long long a, b; } pp;
      pp.a = *(const unsigned long long*)pa;
      pp.b = *(const unsigned long long*)(pa + 8);
      const short8 pf = __builtin_bit_cast(short8, pp);
#pragma unroll
      for (int nt = 0; nt < 4; ++nt) {
        const int cl = cs * 64 + nt * 16 + lm;
        const short8 vf = __builtin_bit_cast(
            short8,
            *(const intx4*)(vbp + cl * 128 + (((ks * 4 + lq) ^ (lm & 7)) * 16)));
        acc[nt] = __builtin_amdgcn_mfma_f32_16x16x32_bf16(pf, vf, acc[nt],
                                                          0, 0, 0);
      }
    }
  }

  // ---- epilogue iteration: PV(63), parity 1 ----
  asm volatile("s_waitcnt lgkmcnt(0)" ::: "memory");
  __builtin_amdgcn_s_barrier();
  {
    const unsigned char* vbp = smem + (1 << 14);
    const unsigned char* pbp = smem + 32768 + 8704 + wg * 2176;
#pragma unroll
    for (int ks = 0; ks < 2; ++ks) {
      const unsigned char* pa = pbp + lm * 136 + ks * 64 + lq * 16;
      struct U128 { unsigned long long a, b; } pp;
      pp.a = *(const unsigned long long*)pa;
      pp.b = *(const unsigned long long*)(pa + 8);
      const short8 pf = __builtin_bit_cast(short8, pp);
#pragma unroll
      for (int nt = 0; nt < 4; ++nt) {
        const int cl = cs * 64 + nt * 16 + lm;
        const short8 vf = __builtin_bit_cast(
            short8,
            *(const intx4*)(vbp + cl * 128 + (((ks * 4 + lq) ^ (lm & 7)) * 16)));
        acc[nt] = __builtin_amdgcn_mfma_f32_16x16x32_bf16(pf, vf, acc[nt],
                                                          0, 0, 0);
      }
    }
  }

  // combine partial lsum across the cs wave pair (each saw half the j's)
  __syncthreads();
  floatx4 lv;
#pragma unroll
  for (int r = 0; r < 4; ++r) lv[r] = lsum[r];
  *(floatx4*)(smem + ((wave * 64 + lane) << 4)) = lv;
  __syncthreads();
  const floatx4 lpart = *(const floatx4*)(smem + (((wave ^ 1) * 64 + lane) << 4));

  float inv[4];
#pragma unroll
  for (int r = 0; r < 4; ++r) {
    float v = lsum[r] + lpart[r];
    v += __shfl_xor(v, 1);
    v += __shfl_xor(v, 2);
    v += __shfl_xor(v, 4);
    v += __shfl_xor(v, 8);
    inv[r] = 1.0f / v;
  }

  const float gm = gamma_p[0];
#pragma unroll
  for (int nt = 0; nt < 4; ++nt) {
#pragma unroll
    for (int r = 0; r < 4; ++r) {
      const int c = ch * 128 + cs * 64 + nt * 16 + lm;
      const int i = i0 + wg * 16 + lq * 4 + r;
      const size_t idx = (size_t)(b * CCH + c) * NN + i;
      out[idx] = gm * sat(acc[nt][r] * inv[r]) + x[idx];
    }
  }
}

extern "C" void kernel_launch(void* const* d_in, const int* in_sizes, int n_in,
                              void* d_out, int out_size, void* d_ws, size_t ws_size,
                              hipStream_t stream) {
  (void)in_sizes; (void)n_in; (void)out_size; (void)ws_size;
  const float* x     = (const float*)d_in[0];
  const float* Wq    = (const float*)d_in[1];
  const float* bq    = (const float*)d_in[2];
  const float* Wk    = (const float*)d_in[3];
  const float* bk    = (const float*)d_in[4];
  const float* Wv    = (const float*)d_in[5];
  const float* bv    = (const float*)d_in[6];
  const float* gamma = (const float*)d_in[7];

  unsigned short* qT = (unsigned short*)d_ws;              // 1 MiB
  unsigned short* kT = qT + (size_t)NB * NN * CRD;         // 1 MiB
  unsigned short* vv = kT + (size_t)NB * NN * CRD;         // 8 MiB

  gemm_qkv_fused<<<dim3(64, 2, 4), 256, 0, stream>>>(x, Wq, bq, Wk, bk, Wv, bv,
                                                     qT, kT, vv);
  attn_kernel<<<dim3(512, 1, 1), 512, 0, stream>>>(x, gamma, qT, kT, vv,
                                                   (float*)d_out);
}

// Round 12
// 159.126 us; speedup vs baseline: 1.0993x; 1.0626x over previous
//
#include <hip/hip_runtime.h>
#include <hip/hip_bf16.h>

#define NB 4
#define CCH 256
#define CRD 32
#define NN 4096

typedef __attribute__((ext_vector_type(8))) short short8;
typedef __attribute__((ext_vector_type(4))) float floatx4;
typedef __attribute__((ext_vector_type(4))) int intx4;
typedef __attribute__((ext_vector_type(2))) unsigned int uintx2;

__device__ __forceinline__ unsigned short f2bf(float f) {
  unsigned u = __builtin_bit_cast(unsigned, f);
  u += 0x7FFFu + ((u >> 16) & 1u);
  return (unsigned short)(u >> 16);
}

// Clamped convert: finite bf16 regardless of input (NaN -> -1e4 via IEEE
// maxNum/minNum, +-inf -> +-1e4). Legit qkv values |v| < ~20: transparent.
__device__ __forceinline__ unsigned short f2bf_c(float f) {
  f = fminf(fmaxf(f, -1.0e4f), 1.0e4f);
  unsigned u = __builtin_bit_cast(unsigned, f);
  u += 0x7FFFu + ((u >> 16) & 1u);
  return (unsigned short)(u >> 16);
}

__device__ __forceinline__ unsigned pack2c(float a, float b) {
  return (unsigned)f2bf_c(a) | ((unsigned)f2bf_c(b) << 16);
}

// Output sanitizer: NaN -> -1e30 (IEEE maxNum), +-inf -> +-1e30.
__device__ __forceinline__ float sat(float v) {
  return fminf(fmaxf(v, -1.0e30f), 1.0e30f);
}

__device__ __forceinline__ short8 ld_frag_g(const unsigned short* p) {
  return __builtin_bit_cast(short8, *(const intx4*)p);
}

// ---------------------------------------------------------------------------
// Kernel 1: fused transpose + QKV GEMM -- round-9 version verbatim (best
// measured total; r10's variant regressed).
// ---------------------------------------------------------------------------
__global__ __launch_bounds__(256) void gemm_qkv_fused(
    const float* __restrict__ x,
    const float* __restrict__ Wq, const float* __restrict__ bq,
    const float* __restrict__ Wk, const float* __restrict__ bk,
    const float* __restrict__ Wv, const float* __restrict__ bv,
    unsigned short* __restrict__ qT, unsigned short* __restrict__ kT,
    unsigned short* __restrict__ vv)
{
  __shared__ __align__(16) unsigned short xs[64 * 264];
  __shared__ __align__(16) unsigned short ws[64 * 264];

  const int tid  = threadIdx.x;
  const int wave = tid >> 6;
  const int lane = tid & 63;
  const int lq   = lane >> 4;
  const int lm   = lane & 15;
  const int n0   = blockIdx.x << 6;
  const int mg   = blockIdx.y;
  const int b    = blockIdx.z;

  {
    const int nn = lane;
    const int cg = wave;
    const float* xb = x + ((size_t)b << 20) + n0 + nn;
#pragma unroll
    for (int it = 0; it < 16; ++it) {
      const int c0 = it * 16 + cg * 4;
      const float v0 = xb[(size_t)(c0 + 0) << 12];
      const float v1 = xb[(size_t)(c0 + 1) << 12];
      const float v2 = xb[(size_t)(c0 + 2) << 12];
      const float v3 = xb[(size_t)(c0 + 3) << 12];
      uintx2 u;
      u[0] = pack2c(v0, v1);
      u[1] = pack2c(v2, v3);
      *(uintx2*)(xs + nn * 264 + c0) = u;
    }
  }

  const int mt_lo = mg ? 3 : 0;
  const int mt_hi = mg ? 5 : 3;

  for (int mt = mt_lo; mt < mt_hi; ++mt) {
#pragma unroll
    for (int i = 0; i < 16; ++i) {
      const int u  = i * 256 + tid;
      const int m  = u >> 6;
      const int o4 = (u & 63) * 4;
      const float* src = (mt == 0)
          ? (m < 32 ? Wq + (size_t)m * CCH : Wk + (size_t)(m - 32) * CCH)
          : Wv + (size_t)((mt - 1) * 64 + m) * CCH;
      const floatx4 f = *(const floatx4*)(src + o4);
      uintx2 uu;
      uu[0] = pack2c(f[0], f[1]);
      uu[1] = pack2c(f[2], f[3]);
      *(uintx2*)(ws + m * 264 + o4) = uu;
    }
    __syncthreads();

    floatx4 acc[4];
#pragma unroll
    for (int t = 0; t < 4; ++t) acc[t] = (floatx4){0.f, 0.f, 0.f, 0.f};

#pragma unroll
    for (int k0 = 0; k0 < 8; ++k0) {
      short8 af[4];
#pragma unroll
      for (int ms = 0; ms < 4; ++ms)
        af[ms] = __builtin_bit_cast(short8,
            *(const intx4*)(ws + (ms * 16 + lm) * 264 + k0 * 32 + lq * 8));
      const short8 bf = __builtin_bit_cast(short8,
          *(const intx4*)(xs + (wave * 16 + lm) * 264 + k0 * 32 + lq * 8));
#pragma unroll
      for (int ms = 0; ms < 4; ++ms)
        acc[ms] = __builtin_amdgcn_mfma_f32_16x16x32_bf16(af[ms], bf,
                                                          acc[ms], 0, 0, 0);
    }
    __syncthreads();

    if (mt == 0) {
      const int n = n0 + wave * 16 + lm;
#pragma unroll
      for (int ms = 0; ms < 4; ++ms) {
        const int d0 = (ms & 1) * 16 + lq * 4;
        const float* bias = (ms < 2) ? bq : bk;
        unsigned short* dst = (ms < 2) ? qT : kT;
        uintx2 u;
        u[0] = pack2c(acc[ms][0] + bias[d0],     acc[ms][1] + bias[d0 + 1]);
        u[1] = pack2c(acc[ms][2] + bias[d0 + 2], acc[ms][3] + bias[d0 + 3]);
        *(uintx2*)(dst + (size_t)(b * NN + n) * CRD + d0) = u;
      }
    } else {
      const int cb = (mt - 1) * 64;
      unsigned short* vb2 = ws;
#pragma unroll
      for (int ms = 0; ms < 4; ++ms)
#pragma unroll
        for (int r = 0; r < 4; ++r) {
          const int c = ms * 16 + lq * 4 + r;
          vb2[c * 64 + wave * 16 + lm] = f2bf_c(acc[ms][r] + bv[cb + c]);
        }
      __syncthreads();
#pragma unroll
      for (int it = 0; it < 2; ++it) {
        const int u = it * 256 + tid;
        const int m = u >> 3;
        const int o = (u & 7) * 8;
        *(intx4*)(vv + (size_t)(b * CCH + cb + m) * NN + n0 + o) =
            *(const intx4*)(vb2 + m * 64 + o);
      }
      __syncthreads();
    }
  }
}

// ---------------------------------------------------------------------------
// Kernel 2: attention. Main loop/layout/grid = round-9 VERBATIM (77.6-80.2
// us across three builds; all loop restructures r2-r11 regressed or nulled).
// Round-12 delta: COALESCED EPILOGUE. Old tail: 32 scalar 4B x-loads + 32
// scalar 4B out-stores per thread, lanes striding 16KB (64 transactions per
// wave-instr). New tail: scale+sat acc in-register (each thread owns its
// rows' inv), stage olds[256c][68i] fp32 in LDS (69.6KB, fits the existing
// 82.9KB block), then 8 float4 passes: out = gm*ov + x, fully coalesced.
// ---------------------------------------------------------------------------
__global__ __launch_bounds__(512) void attn_kernel(
    const float* __restrict__ x, const float* __restrict__ gamma_p,
    const unsigned short* __restrict__ qT, const unsigned short* __restrict__ kT,
    const unsigned short* __restrict__ vv, float* __restrict__ out)
{
  // [0,65536): V double buffer (2 x 256c x 64j bf16, swizzled)
  // [65536, +17408): P double buffer (2 parity x 4 wg x 16 i x 68col shorts)
  // epilogue overlay: olds float[256][68] = 69632 B from base
  __shared__ __align__(16) unsigned char smem[65536 + 2 * 4 * 2176];

  const int tid  = threadIdx.x;
  const int wave = tid >> 6;
  const int wg   = wave >> 1;
  const int cs   = wave & 1;
  const int lane = tid & 63;
  const int lq   = lane >> 4;
  const int lm   = lane & 15;
  const int xcd = blockIdx.x & 7;
  const int pos = blockIdx.x >> 3;
  const int b   = xcd >> 1;
  const int i0  = (((xcd & 1) << 5) | pos) << 6;

  const unsigned short* kTb = kT + (size_t)b * NN * CRD;
  const unsigned short* vb  = vv + (size_t)b * CCH * NN;

  const short8 qf =
      ld_frag_g(qT + (size_t)(b * NN + i0 + wg * 16 + lm) * CRD + lq * 8);

  int vs_g[4];
  int vs_off[4];
#pragma unroll
  for (int m = 0; m < 4; ++m) {
    const int u  = m * 512 + tid;
    const int c  = u >> 3;
    const int jb = u & 7;
    vs_g[m]   = c * NN + jb * 8;
    vs_off[m] = c * 128 + ((jb ^ (c & 7)) * 16);
  }

  floatx4 acc[8];
#pragma unroll
  for (int t = 0; t < 8; ++t) acc[t] = (floatx4){0.f, 0.f, 0.f, 0.f};
  float lsum[4] = {0.f, 0.f, 0.f, 0.f};

  const floatx4 zf = {0.f, 0.f, 0.f, 0.f};

  // ---- prologue: build window 0 in parity 0, then prefetch window 1 ----
  intx4 vreg[4];
#pragma unroll
  for (int m = 0; m < 4; ++m)
    vreg[m] = *(const intx4*)(vb + vs_g[m]);
  short8 kf[2];
#pragma unroll
  for (int jt = 0; jt < 2; ++jt)
    kf[jt] = ld_frag_g(kTb + (size_t)((cs * 2 + jt) * 16 + lm) * CRD + lq * 8);

#pragma unroll
  for (int m = 0; m < 4; ++m)
    *(intx4*)(smem + vs_off[m]) = vreg[m];
  {
    unsigned char* pb0 = smem + 65536 + wg * 2176;
#pragma unroll
    for (int jt = 0; jt < 2; ++jt) {
      const floatx4 S = __builtin_amdgcn_mfma_f32_16x16x32_bf16(
          qf, kf[jt], zf, 0, 0, 0);
#pragma unroll
      for (int r = 0; r < 4; ++r) {
        const float p = __expf(fminf(fmaxf(S[r], -40.f), 40.f));
        lsum[r] += p;
        *(unsigned short*)(pb0 + (lq * 4 + r) * 136 +
                           (((cs * 2 + jt) * 16 + lm) << 1)) = f2bf(p);
      }
    }
  }
#pragma unroll
  for (int m = 0; m < 4; ++m)
    vreg[m] = *(const intx4*)(vb + vs_g[m] + 64);
#pragma unroll
  for (int jt = 0; jt < 2; ++jt)
    kf[jt] = ld_frag_g(kTb + (size_t)(64 + (cs * 2 + jt) * 16 + lm) * CRD +
                       lq * 8);

  // ---- main loop: k = 0..62, one lgkm-barrier per iter, straight-line ----
#pragma unroll 1
  for (int k = 0; k < 63; ++k) {
    asm volatile("s_waitcnt lgkmcnt(0)" ::: "memory");
    __builtin_amdgcn_s_barrier();

    unsigned char* vbp = smem + ((k & 1) << 15);
    unsigned char* pbp = smem + 65536 + (k & 1) * 8704 + wg * 2176;
    unsigned char* vbn = smem + (((k + 1) & 1) << 15);
    unsigned char* pbn = smem + 65536 + ((k + 1) & 1) * 8704 + wg * 2176;

    // stage V(k+1) into parity k+1 (vreg prefetched last iter)
#pragma unroll
    for (int m = 0; m < 4; ++m)
      *(intx4*)(vbn + vs_off[m]) = vreg[m];

    // QK(k+1) + exp + P-store(k+1) -> parity k+1 (independent of PV(k))
#pragma unroll
    for (int jt = 0; jt < 2; ++jt) {
      const floatx4 S = __builtin_amdgcn_mfma_f32_16x16x32_bf16(
          qf, kf[jt], zf, 0, 0, 0);
#pragma unroll
      for (int r = 0; r < 4; ++r) {
        const float p = __expf(fminf(fmaxf(S[r], -40.f), 40.f));
        lsum[r] += p;
        *(unsigned short*)(pbn + (lq * 4 + r) * 136 +
                           (((cs * 2 + jt) * 16 + lm) << 1)) = f2bf(p);
      }
    }

    // prefetch window k+2 (clamped; redundant at k=62, branch-free body)
    {
      const int j2 = ((k + 2 < 64) ? (k + 2) : 63) << 6;
#pragma unroll
      for (int m = 0; m < 4; ++m)
        vreg[m] = *(const intx4*)(vb + vs_g[m] + j2);
#pragma unroll
      for (int jt = 0; jt < 2; ++jt)
        kf[jt] = ld_frag_g(kTb +
                           (size_t)(j2 + (cs * 2 + jt) * 16 + lm) * CRD + lq * 8);
    }

    // PV(k): this wave's 128-col c-half; reads V/P parity k
#pragma unroll
    for (int ks = 0; ks < 2; ++ks) {
      const unsigned char* pa = pbp + lm * 136 + ks * 64 + lq * 16;
      struct U128 { unsigned long long a, b; } pp;
      pp.a = *(const unsigned long long*)pa;
      pp.b = *(const unsigned long long*)(pa + 8);
      const short8 pf = __builtin_bit_cast(short8, pp);
#pragma unroll
      for (int nt = 0; nt < 8; ++nt) {
        const int c = cs * 128 + nt * 16 + lm;
        const short8 vf = __builtin_bit_cast(
            short8,
            *(const intx4*)(vbp + c * 128 + (((ks * 4 + lq) ^ (lm & 7)) * 16)));
        acc[nt] = __builtin_amdgcn_mfma_f32_16x16x32_bf16(pf, vf, acc[nt],
                                                          0, 0, 0);
      }
    }
  }

  // ---- epilogue iteration: PV(63), parity 1 ----
  asm volatile("s_waitcnt lgkmcnt(0)" ::: "memory");
  __builtin_amdgcn_s_barrier();
  {
    const unsigned char* vbp = smem + (1 << 15);
    const unsigned char* pbp = smem + 65536 + 8704 + wg * 2176;
#pragma unroll
    for (int ks = 0; ks < 2; ++ks) {
      const unsigned char* pa = pbp + lm * 136 + ks * 64 + lq * 16;
      struct U128 { unsigned long long a, b; } pp;
      pp.a = *(const unsigned long long*)pa;
      pp.b = *(const unsigned long long*)(pa + 8);
      const short8 pf = __builtin_bit_cast(short8, pp);
#pragma unroll
      for (int nt = 0; nt < 8; ++nt) {
        const int c = cs * 128 + nt * 16 + lm;
        const short8 vf = __builtin_bit_cast(
            short8,
            *(const intx4*)(vbp + c * 128 + (((ks * 4 + lq) ^ (lm & 7)) * 16)));
        acc[nt] = __builtin_amdgcn_mfma_f32_16x16x32_bf16(pf, vf, acc[nt],
                                                          0, 0, 0);
      }
    }
  }

  // ---- lsum combine across the cs wave pair (unchanged math) ----
  __syncthreads();
  floatx4 lv;
#pragma unroll
  for (int r = 0; r < 4; ++r) lv[r] = lsum[r];
  *(floatx4*)(smem + ((wave * 64 + lane) << 4)) = lv;
  __syncthreads();
  const floatx4 lpart = *(const floatx4*)(smem + (((wave ^ 1) * 64 + lane) << 4));

  float inv[4];
#pragma unroll
  for (int r = 0; r < 4; ++r) {
    float v = lsum[r] + lpart[r];
    v += __shfl_xor(v, 1);
    v += __shfl_xor(v, 2);
    v += __shfl_xor(v, 4);
    v += __shfl_xor(v, 8);
    inv[r] = 1.0f / v;
  }

  // ---- NEW: coalesced epilogue via olds[256 c][68 i] fp32 overlay ----
  __syncthreads();   // lpart reads done; smem reusable as olds
  float* olds = (float*)smem;
  {
    const int ib = wg * 16 + lq * 4;   // this thread's 4 consecutive i rows
#pragma unroll
    for (int nt = 0; nt < 8; ++nt) {
      const int c = cs * 128 + nt * 16 + lm;
      floatx4 o;
#pragma unroll
      for (int r = 0; r < 4; ++r) o[r] = sat(acc[nt][r] * inv[r]);
      *(floatx4*)(olds + c * 68 + ib) = o;
    }
  }
  __syncthreads();

  const float gm = gamma_p[0];
#pragma unroll
  for (int pass = 0; pass < 8; ++pass) {
    const int c  = pass * 32 + (tid >> 4);
    const int i4 = (tid & 15) * 4;
    const floatx4 ov = *(const floatx4*)(olds + c * 68 + i4);
    const size_t idx = (size_t)(b * CCH + c) * NN + i0 + i4;
    const floatx4 xv = *(const floatx4*)(x + idx);
    floatx4 o;
#pragma unroll
    for (int e = 0; e < 4; ++e)
      o[e] = gm * ov[e] + xv[e];
    *(floatx4*)(out + idx) = o;
  }
}

extern "C" void kernel_launch(void* const* d_in, const int* in_sizes, int n_in,
                              void* d_out, int out_size, void* d_ws, size_t ws_size,
                              hipStream_t stream) {
  (void)in_sizes; (void)n_in; (void)out_size; (void)ws_size;
  const float* x     = (const float*)d_in[0];
  const float* Wq    = (const float*)d_in[1];
  const float* bq    = (const float*)d_in[2];
  const float* Wk    = (const float*)d_in[3];
  const float* bk    = (const float*)d_in[4];
  const float* Wv    = (const float*)d_in[5];
  const float* bv    = (const float*)d_in[6];
  const float* gamma = (const float*)d_in[7];

  unsigned short* qT = (unsigned short*)d_ws;              // 1 MiB
  unsigned short* kT = qT + (size_t)NB * NN * CRD;         // 1 MiB
  unsigned short* vv = kT + (size_t)NB * NN * CRD;         // 8 MiB

  gemm_qkv_fused<<<dim3(64, 2, 4), 256, 0, stream>>>(x, Wq, bq, Wk, bk, Wv, bv,
                                                     qT, kT, vv);
  attn_kernel<<<dim3(256, 1, 1), 512, 0, stream>>>(x, gamma, qT, kT, vv,
                                                   (float*)d_out);
}